// Round 7
// baseline (238.202 us; speedup 1.0000x reference)
//
#include <hip/hip_runtime.h>
#include <cstdint>
#include <cstddef>

#define DD 128
#define KK 32
constexpr float EPS = 1e-8f;

typedef __bf16 bf16x8 __attribute__((ext_vector_type(8)));
typedef float f32x4 __attribute__((ext_vector_type(4)));

__device__ __forceinline__ unsigned short f2bf(float x) {
    union { float f; uint32_t u; } v; v.f = x;
    uint32_t r = v.u + 0x7FFFu + ((v.u >> 16) & 1u);   // RNE
    return (unsigned short)(r >> 16);
}
__device__ __forceinline__ float bflo(uint32_t w) {
    union { uint32_t u; float f; } v; v.u = w << 16; return v.f;
}
__device__ __forceinline__ float bfhi(uint32_t w) {
    union { uint32_t u; float f; } v; v.u = w & 0xFFFF0000u; return v.f;
}

// DPP quad_perm fold: x += quad_perm<CTRL>(x). VALU pipe, no LDS.
// xor1 = [1,0,3,2] = 0xB1 ; xor2 = [2,3,0,1] = 0x4E.
template <int CTRL>
__device__ __forceinline__ float dpp_fold(float x) {
    union { float f; int i; } u, r;
    u.f = x;
    r.i = __builtin_amdgcn_update_dpp(0, u.i, CTRL, 0xF, 0xF, false);
    return x + r.f;
}
// After both steps every lane holds the sum of its 4-lane group {m&~3..m|3}.
__device__ __forceinline__ f32x4 fold4(f32x4 v) {
    #pragma unroll
    for (int c = 0; c < 4; ++c) {
        float x = v[c];
        x = dpp_fold<0xB1>(x);
        x = dpp_fold<0x4E>(x);
        v[c] = x;
    }
    return v;
}

// ---------------- prep kernel: all format conversions in ONE launch ---------
// Xf[rg][c][mm][8]: row = rg*16+mm, d = c*8+j  -> off = rg*2048 + c*128 + mm*8
// Wf[k][eg][c][mm][8]: W[k][d=c*8+j][e=eg*16+mm]
__global__ __launch_bounds__(256) void prep_kernel(
    const float* __restrict__ x1, const float* __restrict__ x2,
    const float* __restrict__ W1, const float* __restrict__ W2,
    __bf16* __restrict__ X1f, __bf16* __restrict__ X2f,
    __bf16* __restrict__ W1f, __bf16* __restrict__ W2f,
    int cvt_half, int wf_half)
{
    int bb = blockIdx.x;
    if (bb < 2 * cvt_half) {
        const float* src; __bf16* dst;
        if (bb >= cvt_half) { src = x2; dst = X2f; bb -= cvt_half; }
        else                { src = x1; dst = X1f; }
        int idx = bb * 256 + threadIdx.x;
        int mm = idx & 15, c = (idx >> 4) & 15, rg = idx >> 8;
        const float* p = src + (size_t)(rg * 16 + mm) * DD + c * 8;
        float4 f0 = *reinterpret_cast<const float4*>(p);
        float4 f1 = *reinterpret_cast<const float4*>(p + 4);
        ushort4 o0, o1;
        o0.x = f2bf(f0.x); o0.y = f2bf(f0.y); o0.z = f2bf(f0.z); o0.w = f2bf(f0.w);
        o1.x = f2bf(f1.x); o1.y = f2bf(f1.y); o1.z = f2bf(f1.z); o1.w = f2bf(f1.w);
        size_t off = (size_t)rg * 2048 + (size_t)c * 128 + (size_t)mm * 8;
        *reinterpret_cast<ushort4*>(dst + off)     = o0;
        *reinterpret_cast<ushort4*>(dst + off + 4) = o1;
    } else {
        bb -= 2 * cvt_half;
        const float* W; __bf16* Wf;
        if (bb >= wf_half) { W = W2; Wf = W2f; bb -= wf_half; }
        else               { W = W1; Wf = W1f; }
        int idx = bb * 256 + threadIdx.x;
        int mm = idx & 15;
        int c  = (idx >> 4) & 15;
        int eg = (idx >> 8) & 7;
        int k  = idx >> 11;
        const float* Wk = W + (size_t)k * DD * DD;
        int e = eg * 16 + mm;
        ushort4 o0, o1;
        o0.x = f2bf(Wk[(size_t)(c * 8 + 0) * DD + e]);
        o0.y = f2bf(Wk[(size_t)(c * 8 + 1) * DD + e]);
        o0.z = f2bf(Wk[(size_t)(c * 8 + 2) * DD + e]);
        o0.w = f2bf(Wk[(size_t)(c * 8 + 3) * DD + e]);
        o1.x = f2bf(Wk[(size_t)(c * 8 + 4) * DD + e]);
        o1.y = f2bf(Wk[(size_t)(c * 8 + 5) * DD + e]);
        o1.z = f2bf(Wk[(size_t)(c * 8 + 6) * DD + e]);
        o1.w = f2bf(Wk[(size_t)(c * 8 + 7) * DD + e]);
        size_t off = ((size_t)(k * 8 + eg)) * 2048 + (size_t)c * 128 + (size_t)mm * 8;
        *reinterpret_cast<ushort4*>(Wf + off)     = o0;
        *reinterpret_cast<ushort4*>(Wf + off + 4) = o1;
    }
}

// ---------------- main fused kernel ----------------
// 1D grid 16384. XCD decode: xcd=b&7, k=(b>>3)&31 (fast), nt = 64-row tile.
// Block = 4 waves = (row-half rh) x (col-half eh). Each wave owns 32 rows x
// 64 cols of BOTH transforms (acc = 2mat x 2rt x 4et = 64 regs): the
// x1t.x2t dot is computed entirely in-register -> no LDS tile exchange,
// symmetric epilogue, ONE barrier. Folds use DPP quad_perm (VALU pipe).
__global__ __launch_bounds__(256, 3) void ntn_main(
    const __bf16* __restrict__ X1f, const __bf16* __restrict__ X2f,
    const __bf16* __restrict__ W1f, const __bf16* __restrict__ W2f,
    const float* __restrict__ V, const float* __restrict__ bias,
    float* __restrict__ out, int nt_per_xcd)
{
    __shared__ __align__(16) float sRed[3][2][4][64];   // 6 KB [qty][eh][grp][row]
    __shared__ float sP2[4][64];                        // 1 KB part2 partials

    const int b    = blockIdx.x;
    const int xcd  = b & 7;
    const int k    = (b >> 3) & 31;
    const int nt   = xcd * nt_per_xcd + (b >> 8);
    const int tid  = threadIdx.x;
    const int wave = tid >> 6;
    const int lane = tid & 63;
    const int m    = lane & 15;
    const int quad = lane >> 4;
    const int rh   = wave & 1;      // row half (32 rows each)
    const int eh   = wave >> 1;     // column half (64 cols each)

    f32x4 acc[2][2][4];             // [mat][rt][et]
    #pragma unroll
    for (int mat = 0; mat < 2; ++mat)
        #pragma unroll
        for (int rt = 0; rt < 2; ++rt)
            #pragma unroll
            for (int et = 0; et < 4; ++et)
                acc[mat][rt][et] = f32x4{0.f, 0.f, 0.f, 0.f};

    const __bf16* W1p = W1f + (size_t)k * 16384;
    const __bf16* W2p = W2f + (size_t)k * 16384;
    const int rgb = nt * 4 + rh * 2;

    #pragma unroll
    for (int ks = 0; ks < 4; ++ks) {
        bf16x8 a[2][2], bb[2][4];
        #pragma unroll
        for (int rt = 0; rt < 2; ++rt) {
            const size_t aoff = (size_t)(rgb + rt) * 2048 + ks * 512 + lane * 8;
            a[0][rt] = *reinterpret_cast<const bf16x8*>(X1f + aoff);
            a[1][rt] = *reinterpret_cast<const bf16x8*>(X2f + aoff);
        }
        #pragma unroll
        for (int et = 0; et < 4; ++et) {
            const size_t boff = (size_t)(eh * 4 + et) * 2048 + ks * 512 + lane * 8;
            bb[0][et] = *reinterpret_cast<const bf16x8*>(W1p + boff);
            bb[1][et] = *reinterpret_cast<const bf16x8*>(W2p + boff);
        }
        #pragma unroll
        for (int mat = 0; mat < 2; ++mat)
            #pragma unroll
            for (int et = 0; et < 4; ++et)
                #pragma unroll
                for (int rt = 0; rt < 2; ++rt)
                    acc[mat][rt][et] = __builtin_amdgcn_mfma_f32_16x16x32_bf16(
                        a[mat][rt], bb[mat][et], acc[mat][rt][et], 0, 0, 0);
    }

    // ---- part2: 4 threads per row, each a 64-length quarter of xcat.V[k] ---
    {
        const int row = tid & 63, seg = tid >> 6;
        const __bf16* Xs = (seg < 2) ? X1f : X2f;
        const int c0 = (seg & 1) * 8;
        const size_t base = (size_t)(nt * 4 + (row >> 4)) * 2048 + (size_t)(row & 15) * 8;
        const float* Vp = V + (size_t)k * 256 + seg * 64;
        float p2 = 0.f;
        #pragma unroll
        for (int c = 0; c < 8; ++c) {
            uint4 u = *reinterpret_cast<const uint4*>(Xs + base + (c0 + c) * 128);
            float4 v0 = *reinterpret_cast<const float4*>(Vp + c * 8);
            float4 v1 = *reinterpret_cast<const float4*>(Vp + c * 8 + 4);
            p2 += bflo(u.x) * v0.x + bfhi(u.x) * v0.y
                + bflo(u.y) * v0.z + bfhi(u.y) * v0.w
                + bflo(u.z) * v1.x + bfhi(u.z) * v1.y
                + bflo(u.w) * v1.z + bfhi(u.w) * v1.w;
        }
        sP2[seg][row] = p2;
    }

    // ---- in-register products + DPP folds; LDS only for cross-eh combine ---
    const int grp = m >> 2;
    #pragma unroll
    for (int rt = 0; rt < 2; ++rt) {
        f32x4 pd = {0.f, 0.f, 0.f, 0.f};
        f32x4 q1 = {0.f, 0.f, 0.f, 0.f};
        f32x4 q2 = {0.f, 0.f, 0.f, 0.f};
        #pragma unroll
        for (int et = 0; et < 4; ++et) {
            f32x4 c1 = acc[0][rt][et];
            f32x4 c2 = acc[1][rt][et];
            pd += c1 * c2;
            q1 += c1 * c1;
            q2 += c2 * c2;
        }
        pd = fold4(pd);
        q1 = fold4(q1);
        q2 = fold4(q2);
        if ((m & 3) == 0) {
            const int rb = rh * 32 + rt * 16 + quad * 4;
            *reinterpret_cast<f32x4*>(&sRed[0][eh][grp][rb]) = pd;
            *reinterpret_cast<f32x4*>(&sRed[1][eh][grp][rb]) = q1;
            *reinterpret_cast<f32x4*>(&sRed[2][eh][grp][rb]) = q2;
        }
    }

    __syncthreads();

    if (tid < 64) {
        const int row = tid;
        float dot = 0.f, s1 = 0.f, s2 = 0.f;
        #pragma unroll
        for (int e2 = 0; e2 < 2; ++e2)
            #pragma unroll
            for (int g = 0; g < 4; ++g) {
                dot += sRed[0][e2][g][row];
                s1  += sRed[1][e2][g][row];
                s2  += sRed[2][e2][g][row];
            }
        float p2 = sP2[0][row] + sP2[1][row] + sP2[2][row] + sP2[3][row];
        float n1 = fmaxf(sqrtf(s1), EPS);
        float n2 = fmaxf(sqrtf(s2), EPS);
        float tot = dot / (n1 * n2) + p2 + bias[k];
        out[((size_t)nt * 64 + row) * KK + k] = fmaxf(tot, 0.f);
    }
}

extern "C" void kernel_launch(void* const* d_in, const int* in_sizes, int n_in,
                              void* d_out, int out_size, void* d_ws, size_t ws_size,
                              hipStream_t stream) {
    const float* x1 = (const float*)d_in[0];
    const float* x2 = (const float*)d_in[1];
    const float* W1 = (const float*)d_in[2];
    const float* W2 = (const float*)d_in[3];
    const float* V  = (const float*)d_in[4];
    const float* b  = (const float*)d_in[5];
    float* out = (float*)d_out;

    const int N = in_sizes[0] / DD;   // 32768

    __bf16* X1f = (__bf16*)d_ws;
    __bf16* X2f = X1f + (size_t)N * DD;
    __bf16* W1f = X2f + (size_t)N * DD;
    __bf16* W2f = W1f + (size_t)KK * DD * DD;

    const int cvt_half = N * 16 / 256;            // 2048
    const int wf_half  = KK * DD * DD / 8 / 256;  // 256
    prep_kernel<<<2 * cvt_half + 2 * wf_half, 256, 0, stream>>>(
        x1, x2, W1, W2, X1f, X2f, W1f, W2f, cvt_half, wf_half);

    const int ntiles64 = N / 64;                  // 512
    ntn_main<<<ntiles64 * KK, 256, 0, stream>>>(X1f, X2f, W1f, W2f, V, b, out,
                                                ntiles64 / 8);
}

// Round 10
// 208.665 us; speedup vs baseline: 1.1416x; 1.1416x over previous
//
#include <hip/hip_runtime.h>
#include <cstdint>
#include <cstddef>

#define DD 128
#define KK 32
constexpr float EPS = 1e-8f;

typedef __bf16 bf16x8 __attribute__((ext_vector_type(8)));
typedef float f32x4 __attribute__((ext_vector_type(4)));

__device__ __forceinline__ unsigned short f2bf(float x) {
    union { float f; uint32_t u; } v; v.f = x;
    uint32_t r = v.u + 0x7FFFu + ((v.u >> 16) & 1u);   // RNE
    return (unsigned short)(r >> 16);
}
__device__ __forceinline__ float bflo(uint32_t w) {
    union { uint32_t u; float f; } v; v.u = w << 16; return v.f;
}
__device__ __forceinline__ float bfhi(uint32_t w) {
    union { uint32_t u; float f; } v; v.u = w & 0xFFFF0000u; return v.f;
}

// DPP quad_perm fold over lane-xor 1,2 (VALU pipe, no LDS).
template <int CTRL>
__device__ __forceinline__ float dpp_fold(float x) {
    union { float f; int i; } u, r;
    u.f = x;
    r.i = __builtin_amdgcn_update_dpp(0, u.i, CTRL, 0xF, 0xF, false);
    return x + r.f;
}
__device__ __forceinline__ f32x4 fold4(f32x4 v) {
    #pragma unroll
    for (int c = 0; c < 4; ++c) {
        float x = v[c];
        x = dpp_fold<0xB1>(x);   // xor 1
        x = dpp_fold<0x4E>(x);   // xor 2
        v[c] = x;
    }
    return v;
}

// ---------------- prep kernel (identical to the r7 PASSING version) ---------
// Xf[rg][c][mm][8]: row = rg*16+mm, d = c*8+j  -> off = rg*2048 + c*128 + mm*8
// Wf[k][eg][c][mm][8]: W[k][d=c*8+j][e=eg*16+mm]
__global__ __launch_bounds__(256) void prep_kernel(
    const float* __restrict__ x1, const float* __restrict__ x2,
    const float* __restrict__ W1, const float* __restrict__ W2,
    __bf16* __restrict__ X1f, __bf16* __restrict__ X2f,
    __bf16* __restrict__ W1f, __bf16* __restrict__ W2f,
    int cvt_half, int wf_half)
{
    int bb = blockIdx.x;
    if (bb < 2 * cvt_half) {
        const float* src; __bf16* dst;
        if (bb >= cvt_half) { src = x2; dst = X2f; bb -= cvt_half; }
        else                { src = x1; dst = X1f; }
        int idx = bb * 256 + threadIdx.x;
        int mm = idx & 15, c = (idx >> 4) & 15, rg = idx >> 8;
        const float* p = src + (size_t)(rg * 16 + mm) * DD + c * 8;
        float4 f0 = *reinterpret_cast<const float4*>(p);
        float4 f1 = *reinterpret_cast<const float4*>(p + 4);
        ushort4 o0, o1;
        o0.x = f2bf(f0.x); o0.y = f2bf(f0.y); o0.z = f2bf(f0.z); o0.w = f2bf(f0.w);
        o1.x = f2bf(f1.x); o1.y = f2bf(f1.y); o1.z = f2bf(f1.z); o1.w = f2bf(f1.w);
        size_t off = (size_t)rg * 2048 + (size_t)c * 128 + (size_t)mm * 8;
        *reinterpret_cast<ushort4*>(dst + off)     = o0;
        *reinterpret_cast<ushort4*>(dst + off + 4) = o1;
    } else {
        bb -= 2 * cvt_half;
        const float* W; __bf16* Wf;
        if (bb >= wf_half) { W = W2; Wf = W2f; bb -= wf_half; }
        else               { W = W1; Wf = W1f; }
        int idx = bb * 256 + threadIdx.x;
        int mm = idx & 15;
        int c  = (idx >> 4) & 15;
        int eg = (idx >> 8) & 7;
        int k  = idx >> 11;
        const float* Wk = W + (size_t)k * DD * DD;
        int e = eg * 16 + mm;
        ushort4 o0, o1;
        o0.x = f2bf(Wk[(size_t)(c * 8 + 0) * DD + e]);
        o0.y = f2bf(Wk[(size_t)(c * 8 + 1) * DD + e]);
        o0.z = f2bf(Wk[(size_t)(c * 8 + 2) * DD + e]);
        o0.w = f2bf(Wk[(size_t)(c * 8 + 3) * DD + e]);
        o1.x = f2bf(Wk[(size_t)(c * 8 + 4) * DD + e]);
        o1.y = f2bf(Wk[(size_t)(c * 8 + 5) * DD + e]);
        o1.z = f2bf(Wk[(size_t)(c * 8 + 6) * DD + e]);
        o1.w = f2bf(Wk[(size_t)(c * 8 + 7) * DD + e]);
        size_t off = ((size_t)(k * 8 + eg)) * 2048 + (size_t)c * 128 + (size_t)mm * 8;
        *reinterpret_cast<ushort4*>(Wf + off)     = o0;
        *reinterpret_cast<ushort4*>(Wf + off + 4) = o1;
    }
}

// ---------------- main fused kernel ----------------
// Grid 4096 = 32 k x 128 row-groups (256 rows). XCD decode: xcd=b&7,
// k=(b>>3)&31 fast (output-line merge, W hot in XCD L2), group per-XCD.
// Block = 4 waves, wave = (mat, eh). Each wave caches its B half (W[k][mat],
// 64 cols x 128 d = 16 bf16x8 regs) ONCE, then loops 8 tiles of 32 rows:
// 8 A-loads feed 32 MFMAs. Cross-mat dot via sTile (eh-indexed); DPP folds.
// part2 = xcat.V[k] via the r7-PROVEN VALU seg scheme (32-elem quarters).
__global__ __launch_bounds__(256, 3) void ntn_main(
    const __bf16* __restrict__ X1f, const __bf16* __restrict__ X2f,
    const __bf16* __restrict__ W1f, const __bf16* __restrict__ W2f,
    const float* __restrict__ V, const float* __restrict__ bias,
    float* __restrict__ out, int grp_per_xcd)
{
    __shared__ f32x4 sTile[2][2][4][64];                 // 16 KB [eh][rt][et][lane]
    __shared__ __align__(16) float sRed[3][2][4][36];    // 3.5 KB [qty][eh][grp][row36]
    __shared__ float sP2[8][33];                         // 1 KB [seg][row]

    const int b    = blockIdx.x;
    const int xcd  = b & 7;
    const int k    = (b >> 3) & 31;
    const int grpN = xcd * grp_per_xcd + (b >> 8);   // 256-row group
    const int tid  = threadIdx.x;
    const int wave = tid >> 6;
    const int lane = tid & 63;
    const int m    = lane & 15;
    const int quad = lane >> 4;
    const int mat  = wave >> 1;     // 0: x1/W1, 1: x2/W2
    const int eh   = wave & 1;      // column half (64 cols)

    const __bf16* Xp = mat ? X2f : X1f;
    const __bf16* Wp = (mat ? W2f : W1f) + (size_t)k * 16384;

    // ---- cache B in registers: W[k][mat], cols eh*64.., all 128 d ----
    bf16x8 Bc[4][4];   // [ks][et]
    #pragma unroll
    for (int ks = 0; ks < 4; ++ks)
        #pragma unroll
        for (int et = 0; et < 4; ++et)
            Bc[ks][et] = *reinterpret_cast<const bf16x8*>(
                Wp + (size_t)(eh * 4 + et) * 2048 + ks * 512 + lane * 8);

    const float bk = bias[k];
    const int rg0 = grpN * 16;

    for (int g = 0; g < 8; ++g) {
        const __bf16* Ab = Xp + (size_t)(rg0 + g * 2) * 2048;

        f32x4 acc[2][4];    // [rt][et]
        #pragma unroll
        for (int rt = 0; rt < 2; ++rt)
            #pragma unroll
            for (int et = 0; et < 4; ++et) acc[rt][et] = f32x4{0.f, 0.f, 0.f, 0.f};

        #pragma unroll
        for (int ks = 0; ks < 4; ++ks) {
            bf16x8 a0 = *reinterpret_cast<const bf16x8*>(Ab + (size_t)ks * 512 + lane * 8);
            bf16x8 a1 = *reinterpret_cast<const bf16x8*>(Ab + 2048 + (size_t)ks * 512 + lane * 8);
            #pragma unroll
            for (int et = 0; et < 4; ++et) {
                acc[0][et] = __builtin_amdgcn_mfma_f32_16x16x32_bf16(a0, Bc[ks][et], acc[0][et], 0, 0, 0);
                acc[1][et] = __builtin_amdgcn_mfma_f32_16x16x32_bf16(a1, Bc[ks][et], acc[1][et], 0, 0, 0);
            }
        }

        // ---- tile epilogue: mat1 publishes its acc for the cross-mat dot ---
        if (mat == 1) {
            #pragma unroll
            for (int rt = 0; rt < 2; ++rt)
                #pragma unroll
                for (int et = 0; et < 4; ++et)
                    sTile[eh][rt][et][lane] = acc[rt][et];
        }
        __syncthreads();   // barrier A: sTile visible

        const int grp = m >> 2;
        if (mat == 0) {
            #pragma unroll
            for (int rt = 0; rt < 2; ++rt) {
                f32x4 pd = {0.f, 0.f, 0.f, 0.f};
                f32x4 q1 = {0.f, 0.f, 0.f, 0.f};
                #pragma unroll
                for (int et = 0; et < 4; ++et) {
                    f32x4 c1 = acc[rt][et];
                    f32x4 c2 = sTile[eh][rt][et][lane];
                    pd += c1 * c2;
                    q1 += c1 * c1;
                }
                pd = fold4(pd);
                q1 = fold4(q1);
                if ((m & 3) == 0) {
                    const int rb = rt * 16 + quad * 4;
                    *reinterpret_cast<f32x4*>(&sRed[0][eh][grp][rb]) = pd;
                    *reinterpret_cast<f32x4*>(&sRed[1][eh][grp][rb]) = q1;
                }
            }
        } else {
            #pragma unroll
            for (int rt = 0; rt < 2; ++rt) {
                f32x4 q2 = {0.f, 0.f, 0.f, 0.f};
                #pragma unroll
                for (int et = 0; et < 4; ++et) q2 += acc[rt][et] * acc[rt][et];
                q2 = fold4(q2);
                if ((m & 3) == 0) {
                    const int rb = rt * 16 + quad * 4;
                    *reinterpret_cast<f32x4*>(&sRed[2][eh][grp][rb]) = q2;
                }
            }
        }

        // ---- part2 (r7-proven VALU scheme): thread = (row 0..31, seg 0..7),
        // seg -> (mat_s = seg>>2, qtr = seg&3), d in [qtr*32, qtr*32+32).
        // Written between barriers A and B (readers consume after barrier B).
        {
            const int prow = tid & 31;
            const int seg  = tid >> 5;
            const int mats = seg >> 2;
            const int qtr  = seg & 3;
            const __bf16* Xs = mats ? X2f : X1f;
            const size_t base = (size_t)(rg0 + g * 2 + (prow >> 4)) * 2048
                              + (size_t)(prow & 15) * 8;
            const float* Vp = V + (size_t)k * 256 + mats * 128 + qtr * 32;
            float p2 = 0.f;
            #pragma unroll
            for (int c = 0; c < 4; ++c) {
                uint4 u = *reinterpret_cast<const uint4*>(Xs + base + (qtr * 4 + c) * 128);
                float4 v0 = *reinterpret_cast<const float4*>(Vp + c * 8);
                float4 v1 = *reinterpret_cast<const float4*>(Vp + c * 8 + 4);
                p2 += bflo(u.x) * v0.x + bfhi(u.x) * v0.y
                    + bflo(u.y) * v0.z + bfhi(u.y) * v0.w
                    + bflo(u.z) * v1.x + bfhi(u.z) * v1.y
                    + bflo(u.w) * v1.z + bfhi(u.w) * v1.w;
            }
            sP2[seg][prow] = p2;
        }

        __syncthreads();   // barrier B: sRed + sP2 visible

        if (tid < 32) {
            const int row = tid;
            float dot = 0.f, s1 = 0.f, s2 = 0.f;
            #pragma unroll
            for (int e2 = 0; e2 < 2; ++e2)
                #pragma unroll
                for (int gg = 0; gg < 4; ++gg) {
                    dot += sRed[0][e2][gg][row];
                    s1  += sRed[1][e2][gg][row];
                    s2  += sRed[2][e2][gg][row];
                }
            float p2 = 0.f;
            #pragma unroll
            for (int s = 0; s < 8; ++s) p2 += sP2[s][row];
            float n1 = fmaxf(sqrtf(s1), EPS);
            float n2 = fmaxf(sqrtf(s2), EPS);
            float tot = dot / (n1 * n2) + p2 + bk;
            out[((size_t)grpN * 256 + g * 32 + row) * KK + k] = fmaxf(tot, 0.f);
        }
    }
}

extern "C" void kernel_launch(void* const* d_in, const int* in_sizes, int n_in,
                              void* d_out, int out_size, void* d_ws, size_t ws_size,
                              hipStream_t stream) {
    const float* x1 = (const float*)d_in[0];
    const float* x2 = (const float*)d_in[1];
    const float* W1 = (const float*)d_in[2];
    const float* W2 = (const float*)d_in[3];
    const float* V  = (const float*)d_in[4];
    const float* b  = (const float*)d_in[5];
    float* out = (float*)d_out;

    const int N = in_sizes[0] / DD;   // 32768

    __bf16* X1f = (__bf16*)d_ws;
    __bf16* X2f = X1f + (size_t)N * DD;
    __bf16* W1f = X2f + (size_t)N * DD;
    __bf16* W2f = W1f + (size_t)KK * DD * DD;

    const int cvt_half = N * 16 / 256;            // 2048
    const int wf_half  = KK * DD * DD / 8 / 256;  // 256
    prep_kernel<<<2 * cvt_half + 2 * wf_half, 256, 0, stream>>>(
        x1, x2, W1, W2, X1f, X2f, W1f, W2f, cvt_half, wf_half);

    const int groups = N / 256;                   // 128
    ntn_main<<<groups * KK, 256, 0, stream>>>(X1f, X2f, W1f, W2f, V, b, out,
                                              groups / 8);
}

// Round 11
// 207.792 us; speedup vs baseline: 1.1463x; 1.0042x over previous
//
#include <hip/hip_runtime.h>
#include <cstdint>
#include <cstddef>

#define DD 128
#define KK 32
constexpr float EPS = 1e-8f;

typedef __bf16 bf16x8 __attribute__((ext_vector_type(8)));
typedef float f32x4 __attribute__((ext_vector_type(4)));

__device__ __forceinline__ unsigned short f2bf(float x) {
    union { float f; uint32_t u; } v; v.f = x;
    uint32_t r = v.u + 0x7FFFu + ((v.u >> 16) & 1u);   // RNE
    return (unsigned short)(r >> 16);
}
__device__ __forceinline__ __bf16 f2bf16(float x) {
    unsigned short u = f2bf(x);
    __bf16 r; __builtin_memcpy(&r, &u, 2); return r;
}

// DPP quad_perm fold over lane-xor 1,2 (VALU pipe, no LDS).
template <int CTRL>
__device__ __forceinline__ float dpp_fold(float x) {
    union { float f; int i; } u, r;
    u.f = x;
    r.i = __builtin_amdgcn_update_dpp(0, u.i, CTRL, 0xF, 0xF, false);
    return x + r.f;
}
__device__ __forceinline__ f32x4 fold4(f32x4 v) {
    #pragma unroll
    for (int c = 0; c < 4; ++c) {
        float x = v[c];
        x = dpp_fold<0xB1>(x);   // xor 1
        x = dpp_fold<0x4E>(x);   // xor 2
        v[c] = x;
    }
    return v;
}

// ---------------- prep kernel (r7/r10 proven, unchanged) --------------------
// Xf[rg][c][mm][8]: row = rg*16+mm, d = c*8+j  -> off = rg*2048 + c*128 + mm*8
// Wf[k][eg][c][mm][8]: W[k][d=c*8+j][e=eg*16+mm]
__global__ __launch_bounds__(256) void prep_kernel(
    const float* __restrict__ x1, const float* __restrict__ x2,
    const float* __restrict__ W1, const float* __restrict__ W2,
    __bf16* __restrict__ X1f, __bf16* __restrict__ X2f,
    __bf16* __restrict__ W1f, __bf16* __restrict__ W2f,
    int cvt_half, int wf_half)
{
    int bb = blockIdx.x;
    if (bb < 2 * cvt_half) {
        const float* src; __bf16* dst;
        if (bb >= cvt_half) { src = x2; dst = X2f; bb -= cvt_half; }
        else                { src = x1; dst = X1f; }
        int idx = bb * 256 + threadIdx.x;
        int mm = idx & 15, c = (idx >> 4) & 15, rg = idx >> 8;
        const float* p = src + (size_t)(rg * 16 + mm) * DD + c * 8;
        float4 f0 = *reinterpret_cast<const float4*>(p);
        float4 f1 = *reinterpret_cast<const float4*>(p + 4);
        ushort4 o0, o1;
        o0.x = f2bf(f0.x); o0.y = f2bf(f0.y); o0.z = f2bf(f0.z); o0.w = f2bf(f0.w);
        o1.x = f2bf(f1.x); o1.y = f2bf(f1.y); o1.z = f2bf(f1.z); o1.w = f2bf(f1.w);
        size_t off = (size_t)rg * 2048 + (size_t)c * 128 + (size_t)mm * 8;
        *reinterpret_cast<ushort4*>(dst + off)     = o0;
        *reinterpret_cast<ushort4*>(dst + off + 4) = o1;
    } else {
        bb -= 2 * cvt_half;
        const float* W; __bf16* Wf;
        if (bb >= wf_half) { W = W2; Wf = W2f; bb -= wf_half; }
        else               { W = W1; Wf = W1f; }
        int idx = bb * 256 + threadIdx.x;
        int mm = idx & 15;
        int c  = (idx >> 4) & 15;
        int eg = (idx >> 8) & 7;
        int k  = idx >> 11;
        const float* Wk = W + (size_t)k * DD * DD;
        int e = eg * 16 + mm;
        ushort4 o0, o1;
        o0.x = f2bf(Wk[(size_t)(c * 8 + 0) * DD + e]);
        o0.y = f2bf(Wk[(size_t)(c * 8 + 1) * DD + e]);
        o0.z = f2bf(Wk[(size_t)(c * 8 + 2) * DD + e]);
        o0.w = f2bf(Wk[(size_t)(c * 8 + 3) * DD + e]);
        o1.x = f2bf(Wk[(size_t)(c * 8 + 4) * DD + e]);
        o1.y = f2bf(Wk[(size_t)(c * 8 + 5) * DD + e]);
        o1.z = f2bf(Wk[(size_t)(c * 8 + 6) * DD + e]);
        o1.w = f2bf(Wk[(size_t)(c * 8 + 7) * DD + e]);
        size_t off = ((size_t)(k * 8 + eg)) * 2048 + (size_t)c * 128 + (size_t)mm * 8;
        *reinterpret_cast<ushort4*>(Wf + off)     = o0;
        *reinterpret_cast<ushort4*>(Wf + off + 4) = o1;
    }
}

// ---------------- part2 GEMM (r3 proven): p2w[n][k] = xcat[n].V[k] ----------
__global__ __launch_bounds__(256) void part2_kernel(
    const __bf16* __restrict__ X1f, const __bf16* __restrict__ X2f,
    const float* __restrict__ V, float* __restrict__ p2w) {
    const int wave = threadIdx.x >> 6, lane = threadIdx.x & 63;
    const int m = lane & 15, quad = lane >> 4;
    const int rg0 = blockIdx.x * 16 + wave * 4;   // 64 rows per wave

    f32x4 acc[4][2];
    #pragma unroll
    for (int rt = 0; rt < 4; ++rt)
        #pragma unroll
        for (int ct = 0; ct < 2; ++ct) acc[rt][ct] = f32x4{0.f, 0.f, 0.f, 0.f};

    #pragma unroll
    for (int ks = 0; ks < 8; ++ks) {
        const __bf16* Xs = (ks < 4) ? X1f : X2f;
        const int kss = ks & 3;
        bf16x8 a[4];
        #pragma unroll
        for (int rt = 0; rt < 4; ++rt)
            a[rt] = *reinterpret_cast<const bf16x8*>(
                Xs + (size_t)(rg0 + rt) * 2048 + kss * 512 + lane * 8);
        #pragma unroll
        for (int ct = 0; ct < 2; ++ct) {
            // b[lane][j] = V[k=ct*16+m][f=ks*32+quad*8+j]
            const float* p = V + (size_t)(ct * 16 + m) * 256 + ks * 32 + quad * 8;
            float4 v0 = *reinterpret_cast<const float4*>(p);
            float4 v1 = *reinterpret_cast<const float4*>(p + 4);
            bf16x8 b;
            b[0] = f2bf16(v0.x); b[1] = f2bf16(v0.y); b[2] = f2bf16(v0.z); b[3] = f2bf16(v0.w);
            b[4] = f2bf16(v1.x); b[5] = f2bf16(v1.y); b[6] = f2bf16(v1.z); b[7] = f2bf16(v1.w);
            #pragma unroll
            for (int rt = 0; rt < 4; ++rt)
                acc[rt][ct] = __builtin_amdgcn_mfma_f32_16x16x32_bf16(a[rt], b, acc[rt][ct], 0, 0, 0);
        }
    }
    const int row0 = blockIdx.x * 256 + wave * 64;
    #pragma unroll
    for (int rt = 0; rt < 4; ++rt)
        #pragma unroll
        for (int ct = 0; ct < 2; ++ct)
            #pragma unroll
            for (int reg = 0; reg < 4; ++reg)
                p2w[(size_t)(row0 + rt * 16 + quad * 4 + reg) * KK + ct * 16 + m] = acc[rt][ct][reg];
}

// ---------------- main fused kernel ----------------
// Grid 4096 = 32 k x 128 row-groups (256 rows). XCD decode: xcd=b&7,
// k=(b>>3)&31 fast, group per-XCD. Block = 4 waves, wave = (rh, eh):
// 16 rows x 64 cols of BOTH mats. Bc = both W[k] halves register-resident
// (128 VGPR) -> in-register cross-mat dot, NO sTile, ONE barrier per tile
// (double-buffered sRed). part2 precomputed in p2w.
__global__ __launch_bounds__(256, 2) void ntn_main(
    const __bf16* __restrict__ X1f, const __bf16* __restrict__ X2f,
    const __bf16* __restrict__ W1f, const __bf16* __restrict__ W2f,
    const float* __restrict__ p2w, const float* __restrict__ bias,
    float* __restrict__ out, int grp_per_xcd)
{
    __shared__ __align__(16) float sRed[2][3][2][4][36];  // 13.8 KB [buf][qty][eh][grp][row36]

    const int b    = blockIdx.x;
    const int xcd  = b & 7;
    const int k    = (b >> 3) & 31;
    const int grpN = xcd * grp_per_xcd + (b >> 8);   // 256-row group
    const int tid  = threadIdx.x;
    const int wave = tid >> 6;
    const int lane = tid & 63;
    const int m    = lane & 15;
    const int quad = lane >> 4;
    const int rh   = wave & 1;      // row half of the 32-row tile
    const int eh   = wave >> 1;     // column half (64 cols)

    const __bf16* W1p = W1f + (size_t)k * 16384;
    const __bf16* W2p = W2f + (size_t)k * 16384;

    // ---- cache BOTH B halves in registers: 2 mats x 4 ks x 4 et ----
    bf16x8 Bc[2][4][4];
    #pragma unroll
    for (int ks = 0; ks < 4; ++ks)
        #pragma unroll
        for (int et = 0; et < 4; ++et) {
            const size_t boff = (size_t)(eh * 4 + et) * 2048 + ks * 512 + lane * 8;
            Bc[0][ks][et] = *reinterpret_cast<const bf16x8*>(W1p + boff);
            Bc[1][ks][et] = *reinterpret_cast<const bf16x8*>(W2p + boff);
        }

    const float bk = bias[k];
    const int rg0 = grpN * 16;

    for (int g = 0; g < 8; ++g) {
        const size_t abase = (size_t)(rg0 + g * 2 + rh) * 2048;

        f32x4 acc[2][4];    // [mat][et]
        #pragma unroll
        for (int mat = 0; mat < 2; ++mat)
            #pragma unroll
            for (int et = 0; et < 4; ++et) acc[mat][et] = f32x4{0.f, 0.f, 0.f, 0.f};

        #pragma unroll
        for (int ks = 0; ks < 4; ++ks) {
            bf16x8 a1 = *reinterpret_cast<const bf16x8*>(X1f + abase + (size_t)ks * 512 + lane * 8);
            bf16x8 a2 = *reinterpret_cast<const bf16x8*>(X2f + abase + (size_t)ks * 512 + lane * 8);
            #pragma unroll
            for (int et = 0; et < 4; ++et) {
                acc[0][et] = __builtin_amdgcn_mfma_f32_16x16x32_bf16(a1, Bc[0][ks][et], acc[0][et], 0, 0, 0);
                acc[1][et] = __builtin_amdgcn_mfma_f32_16x16x32_bf16(a2, Bc[1][ks][et], acc[1][et], 0, 0, 0);
            }
        }

        // ---- in-register cross-mat epilogue + DPP folds ----
        f32x4 pd = {0.f, 0.f, 0.f, 0.f};
        f32x4 q1 = {0.f, 0.f, 0.f, 0.f};
        f32x4 q2 = {0.f, 0.f, 0.f, 0.f};
        #pragma unroll
        for (int et = 0; et < 4; ++et) {
            f32x4 c1 = acc[0][et];
            f32x4 c2 = acc[1][et];
            pd += c1 * c2;
            q1 += c1 * c1;
            q2 += c2 * c2;
        }
        pd = fold4(pd);
        q1 = fold4(q1);
        q2 = fold4(q2);

        const int buf = g & 1;
        if ((m & 3) == 0) {
            const int grp = m >> 2;
            const int rb  = rh * 16 + quad * 4;
            *reinterpret_cast<f32x4*>(&sRed[buf][0][eh][grp][rb]) = pd;
            *reinterpret_cast<f32x4*>(&sRed[buf][1][eh][grp][rb]) = q1;
            *reinterpret_cast<f32x4*>(&sRed[buf][2][eh][grp][rb]) = q2;
        }

        __syncthreads();   // sRed[buf] visible (next tile writes other buf)

        if (tid < 32) {
            const int row = tid;
            float dot = 0.f, s1 = 0.f, s2 = 0.f;
            #pragma unroll
            for (int e2 = 0; e2 < 2; ++e2)
                #pragma unroll
                for (int gg = 0; gg < 4; ++gg) {
                    dot += sRed[buf][0][e2][gg][row];
                    s1  += sRed[buf][1][e2][gg][row];
                    s2  += sRed[buf][2][e2][gg][row];
                }
            const size_t n = (size_t)grpN * 256 + g * 32 + row;
            float p2 = p2w[n * KK + k];
            float n1 = fmaxf(sqrtf(s1), EPS);
            float n2 = fmaxf(sqrtf(s2), EPS);
            float tot = dot / (n1 * n2) + p2 + bk;
            out[n * KK + k] = fmaxf(tot, 0.f);
        }
    }
}

extern "C" void kernel_launch(void* const* d_in, const int* in_sizes, int n_in,
                              void* d_out, int out_size, void* d_ws, size_t ws_size,
                              hipStream_t stream) {
    const float* x1 = (const float*)d_in[0];
    const float* x2 = (const float*)d_in[1];
    const float* W1 = (const float*)d_in[2];
    const float* W2 = (const float*)d_in[3];
    const float* V  = (const float*)d_in[4];
    const float* b  = (const float*)d_in[5];
    float* out = (float*)d_out;

    const int N = in_sizes[0] / DD;   // 32768

    __bf16* X1f = (__bf16*)d_ws;
    __bf16* X2f = X1f + (size_t)N * DD;
    __bf16* W1f = X2f + (size_t)N * DD;
    __bf16* W2f = W1f + (size_t)KK * DD * DD;
    float*  p2w = (float*)(W2f + (size_t)KK * DD * DD);

    const int cvt_half = N * 16 / 256;            // 2048
    const int wf_half  = KK * DD * DD / 8 / 256;  // 256
    prep_kernel<<<2 * cvt_half + 2 * wf_half, 256, 0, stream>>>(
        x1, x2, W1, W2, X1f, X2f, W1f, W2f, cvt_half, wf_half);

    part2_kernel<<<N / 256, 256, 0, stream>>>(X1f, X2f, V, p2w);

    const int groups = N / 256;                   // 128
    ntn_main<<<groups * KK, 256, 0, stream>>>(X1f, X2f, W1f, W2f, p2w, b, out,
                                              groups / 8);
}